// Round 13
// baseline (42.139 us; speedup 1.0000x reference)
//
#include <hip/hip_runtime.h>

// Inception Temporal Layer — 3 causal VALID conv1d + leaky_relu(0.01).
// x[8192][512][4] f32; w1[16][4][6]; w2[16][16][4]; w3[16][16][13]; out[8192][3][48][16].
// Cone: o3[t<48] <- even o2[0..142] <- o1[0..148] <- x[0..449].
//
// Round 13 = round 8/12 math (MFMA, frag-ready weights in d_ws, 49 MFMA/row)
// restructured to kill per-block cold-entry latency:
//  - 4 rows per block (grid 2048 = exactly 8 blocks/CU, one generation, no ramp)
//  - next row's 20 x-loads prefetched during current row's stage 1 (issue-to-use
//    distance ~ one full row of compute >> HBM/L3 latency)
//  - weight frags loaded once per block (4x amortized)
//  - row-boundary LDS WAR: in-order DS pipe + s_waitcnt lgkmcnt(0) per row
// Per-output accumulation order unchanged since round 8 -> absmax 0.03125.
//
// Frag maps (m89-verified): A row = l&15, k = 8*(l>>4)+e; B col = l&15, same k;
// D col = l&15, row = 4*(l>>4)+r.
// K-orders: stage1 k = kk*4+ch (K=24 pad 32); stages 2/3 k = kk*16+ci
// (K=64; K=208 pad 224) so A-frag = 8 consecutive ci = one ds_read_b128.

typedef __attribute__((ext_vector_type(8))) short bf16x8;
typedef __attribute__((ext_vector_type(4))) float f32x4;
typedef __attribute__((ext_vector_type(4))) unsigned int u32x4;

union FragU { u32x4 u; bf16x8 b; };

__device__ __forceinline__ unsigned short f2bf(float f) {   // RTN-even
    unsigned int u = __builtin_bit_cast(unsigned int, f);
    u += 0x7FFFu + ((u >> 16) & 1u);
    return (unsigned short)(u >> 16);
}
__device__ __forceinline__ unsigned int pack2bf(float lo, float hi) {
    return (unsigned int)f2bf(lo) | ((unsigned int)f2bf(hi) << 16);
}

// d_ws u32 layout (frag-ready B, bf16 pairs; pair kp holds k=2kp lo, 2kp+1 hi):
//   [0..255]     B1[kp*16+co], k = kk*4+ch  (K=24, kp>=12 -> 0)
//   [256..767]   B2[kp*16+co], k = kk*16+ci (K=64)
//   [768..2559]  B3[kp*16+co], k = kk*16+ci (K=208, kk=13 -> 0)
//   f32: [2560..2575] b1, [2576..2591] b2, [2592..2607] b3
__global__ void wtrans_kernel(const float* __restrict__ w1, const float* __restrict__ b1,
                              const float* __restrict__ w2, const float* __restrict__ b2,
                              const float* __restrict__ w3, const float* __restrict__ b3,
                              unsigned int* __restrict__ ws) {
    const int tid = threadIdx.x;                    // 256 threads
    if (tid < 256) {                                // B1: k = kk*4 + ch
        int kp = tid >> 4, co = tid & 15;
        int k0 = 2 * kp, k1 = k0 + 1;
        float v0 = (k0 < 24) ? w1[co * 24 + (k0 & 3) * 6 + (k0 >> 2)] : 0.f;
        float v1 = (k1 < 24) ? w1[co * 24 + (k1 & 3) * 6 + (k1 >> 2)] : 0.f;
        ws[tid] = pack2bf(v0, v1);
    }
    for (int p = tid; p < 512; p += 256) {          // B2: k = kk*16 + ci
        int kp = p >> 4, co = p & 15;
        int k0 = 2 * kp, ci0 = k0 & 15, kk = k0 >> 4;
        ws[256 + p] = pack2bf(w2[co * 64 + ci0 * 4 + kk],
                              w2[co * 64 + (ci0 + 1) * 4 + kk]);
    }
    for (int p = tid; p < 1792; p += 256) {         // B3: k = kk*16 + ci
        int kp = p >> 4, co = p & 15;
        int k0 = 2 * kp, ci0 = k0 & 15, kk = k0 >> 4;
        float v0 = (kk < 13) ? w3[co * 208 + ci0 * 13 + kk] : 0.f;
        float v1 = (kk < 13) ? w3[co * 208 + (ci0 + 1) * 13 + kk] : 0.f;
        ws[768 + p] = pack2bf(v0, v1);
    }
    float* wf = (float*)ws;
    if (tid < 16) { wf[2560 + tid] = b1[tid]; wf[2576 + tid] = b2[tid]; wf[2592 + tid] = b3[tid]; }
}

__global__ __launch_bounds__(64, 2) void itl_kernel(
    const float* __restrict__ x,
    const unsigned int* __restrict__ wt,
    float* __restrict__ out)
{
    __shared__ __align__(16) unsigned short o1b[160 * 24];  // bf16 o1[t][ci], 48B rows
    __shared__ __align__(16) unsigned short o2e[76 * 24];   // bf16 even-o2 [slot][ci]

    const int lane = threadIdx.x;        // 0..63, one wave per block
    const int n0   = blockIdx.x * 4;     // 4 rows per block
    const int co   = lane & 15;          // A-row / B-col / D-col index
    const int g    = lane >> 4;          // 0..3
    const int gh   = g >> 1;             // (l>>5)
    const int cib  = 8 * (g & 1);        // ci base of this lane's A elements

    const float* wf = (const float*)wt;

    // ---- weight fragments + biases, once per block (coalesced from d_ws) ----
    FragU b1f;
    #pragma unroll
    for (int p = 0; p < 4; ++p) b1f.u[p] = wt[(4 * g + p) * 16 + co];
    FragU b2f[2];
    #pragma unroll
    for (int kb = 0; kb < 2; ++kb)
        #pragma unroll
        for (int p = 0; p < 4; ++p)
            b2f[kb].u[p] = wt[256 + (16 * kb + 4 * g + p) * 16 + co];
    FragU b3f[7];
    #pragma unroll
    for (int kb = 0; kb < 7; ++kb)
        #pragma unroll
        for (int p = 0; p < 4; ++p)
            b3f[kb].u[p] = wt[768 + (16 * kb + 4 * g + p) * 16 + co];
    const float bias1 = wf[2560 + co];
    const float bias2 = wf[2576 + co];
    const float bias3 = wf[2592 + co];

    // zero the o2e pad rows 72..75 once (never overwritten; read under zero-B pad)
    if (lane < 48) reinterpret_cast<unsigned int*>(o2e)[72 * 12 + lane] = 0u;

    // ---- preload row n0's x windows ----
    const float4* x4 = reinterpret_cast<const float4*>(x) + (size_t)n0 * 512;
    float4 xa[10], xb[10];
    #pragma unroll
    for (int ti = 0; ti < 10; ++ti) {
        const int r0 = 3 * (16 * ti + co) + 2 * g;   // <= 483; +1 = 484 < 512
        xa[ti] = x4[r0];
        xb[ti] = x4[r0 + 1];
    }

    float* outn = out + (size_t)n0 * 2304;
    #pragma unroll 1
    for (int rr = 0; rr < 4; ++rr) {
        // next row base (rr==3: clamp to current row; loads discarded)
        const float4* xn = x4 + (rr == 3 ? 0 : 512);

        // ---------------- stage 1: 10 tiles, K=24 pad 32 + prefetch next row ---
        #pragma unroll
        for (int ti = 0; ti < 10; ++ti) {
            const int j0 = 16 * ti;
            FragU a;
            a.u[0] = pack2bf(xa[ti].x, xa[ti].y);
            a.u[1] = pack2bf(xa[ti].z, xa[ti].w);
            a.u[2] = pack2bf(xb[ti].x, xb[ti].y);
            a.u[3] = pack2bf(xb[ti].z, xb[ti].w);   // g=3: real data x zero-B = +0
            {   // prefetch next row's window into the just-freed registers
                const int r0 = 3 * (16 * ti + co) + 2 * g;
                xa[ti] = xn[r0];
                xb[ti] = xn[r0 + 1];
            }
            f32x4 acc = {bias1, bias1, bias1, bias1};
            acc = __builtin_amdgcn_mfma_f32_16x16x32_bf16(a.b, b1f.b, acc, 0, 0, 0);
            const int tD = j0 + 4 * g;               // D row = 4*(l>>4)+r
            #pragma unroll
            for (int r = 0; r < 4; ++r) {
                float v = acc[r]; v = fmaxf(v, 0.01f * v);
                o1b[(tD + r) * 24 + co] = f2bf(v);           // rows <= 159 < 160
                if (ti < 3) outn[(tD + r) * 16 + co] = v;    // scale 0, t<48
            }
        }

        // ---------------- stage 2: 9 tiles x 2 k-steps, K=64 -------------------
        #pragma unroll
        for (int ti = 0; ti < 9; ++ti) {
            const int j0 = 16 * ti;
            f32x4 acc = {bias2, bias2, bias2, bias2};
            #pragma unroll
            for (int kb = 0; kb < 2; ++kb) {
                const int row = j0 + co + 2 * (2 * kb + gh);    // <= 149
                FragU a; a.u = *(const u32x4*)&o1b[row * 24 + cib];
                acc = __builtin_amdgcn_mfma_f32_16x16x32_bf16(a.b, b2f[kb].b, acc, 0, 0, 0);
            }
            const int jD = j0 + 4 * g;
            #pragma unroll
            for (int r = 0; r < 4; ++r) {
                float v = acc[r]; v = fmaxf(v, 0.01f * v);
                if ((r & 1) == 0) o2e[((jD + r) >> 1) * 24 + co] = f2bf(v);  // even j
                if (ti < 3) outn[768 + (jD + r) * 16 + co] = v;  // scale 1, j<48
            }
        }

        // ---------------- stage 3: 3 tiles x 7 k-steps, K=208 pad 224 ----------
        #pragma unroll
        for (int ti = 0; ti < 3; ++ti) {
            const int t0 = 16 * ti;
            f32x4 acc = {bias3, bias3, bias3, bias3};
            #pragma unroll
            for (int kb = 0; kb < 7; ++kb) {
                const int row = t0 + co + 2 * (2 * kb + gh);    // <= 73 < 76
                FragU a; a.u = *(const u32x4*)&o2e[row * 24 + cib];
                acc = __builtin_amdgcn_mfma_f32_16x16x32_bf16(a.b, b3f[kb].b, acc, 0, 0, 0);
            }
            const int tD = t0 + 4 * g;
            #pragma unroll
            for (int r = 0; r < 4; ++r) {
                float v = acc[r]; v = fmaxf(v, 0.01f * v);
                outn[1536 + (tD + r) * 16 + co] = v;            // scale 2
            }
        }

        // row boundary: drain LDS ops so next row's o1b/o2e writes can't pass
        // this row's reads (in-order DS pipe + explicit fence, belt & suspenders)
        asm volatile("s_waitcnt lgkmcnt(0)" ::: "memory");
        outn += 2304;
        x4   += 512;
    }
}

extern "C" void kernel_launch(void* const* d_in, const int* in_sizes, int n_in,
                              void* d_out, int out_size, void* d_ws, size_t ws_size,
                              hipStream_t stream) {
    const float* x  = (const float*)d_in[0];
    const float* w1 = (const float*)d_in[1];
    const float* b1 = (const float*)d_in[2];
    const float* w2 = (const float*)d_in[3];
    const float* b2 = (const float*)d_in[4];
    const float* w3 = (const float*)d_in[5];
    const float* b3 = (const float*)d_in[6];
    float* out = (float*)d_out;
    unsigned int* ws = (unsigned int*)d_ws;           // 2608 u32 = 10.4 KB

    wtrans_kernel<<<1, 256, 0, stream>>>(w1, b1, w2, b2, w3, b3, ws);
    itl_kernel<<<2048, 64, 0, stream>>>(x, ws, out);  // 4 rows per 1-wave block
}

// Round 14
// 37.870 us; speedup vs baseline: 1.1127x; 1.1127x over previous
//
#include <hip/hip_runtime.h>

// Inception Temporal Layer — 3 causal VALID conv1d + leaky_relu(0.01).
// x[8192][512][4] f32; w1[16][4][6]; w2[16][16][4]; w3[16][16][13]; out[8192][3][48][16].
// Cone: o3[t<48] <- even o2[0..142] <- o1[0..148] <- x[0..449].
//
// Round 14 = round 8 math EXACTLY (MFMA, frag-ready weights in d_ws, 49
// MFMA/row, 1 wave per row) repackaged as 2048 workgroups x 4 waves to test
// the WG-dispatch-rate theory (8192 single-wave WGs may cost ~100cyc each in
// CP/SPI setup). Waves are fully independent: private LDS slice per wave,
// no barriers. wtrans runs as 64 redundant blocks (identical writes) so its
// wall time ~0.3us. Per-output accumulation order unchanged -> absmax 0.03125.
//
// Frag maps (m89-verified): A row = l&15, k = 8*(l>>4)+e; B col = l&15, same k;
// D col = l&15, row = 4*(l>>4)+r.
// K-orders: stage1 k = kk*4+ch (K=24 pad 32); stages 2/3 k = kk*16+ci
// (K=64; K=208 pad 224) so A-frag = 8 consecutive ci = one ds_read_b128.

typedef __attribute__((ext_vector_type(8))) short bf16x8;
typedef __attribute__((ext_vector_type(4))) float f32x4;
typedef __attribute__((ext_vector_type(4))) unsigned int u32x4;

union FragU { u32x4 u; bf16x8 b; };

__device__ __forceinline__ unsigned short f2bf(float f) {   // RTN-even
    unsigned int u = __builtin_bit_cast(unsigned int, f);
    u += 0x7FFFu + ((u >> 16) & 1u);
    return (unsigned short)(u >> 16);
}
__device__ __forceinline__ unsigned int pack2bf(float lo, float hi) {
    return (unsigned int)f2bf(lo) | ((unsigned int)f2bf(hi) << 16);
}

// d_ws u32 layout (frag-ready B, bf16 pairs; pair kp holds k=2kp lo, 2kp+1 hi):
//   [0..255]     B1[kp*16+co], k = kk*4+ch  (K=24, kp>=12 -> 0)
//   [256..767]   B2[kp*16+co], k = kk*16+ci (K=64)
//   [768..2559]  B3[kp*16+co], k = kk*16+ci (K=208, kk=13 -> 0)
//   f32: [2560..2575] b1, [2576..2591] b2, [2592..2607] b3
// 64 blocks all write identical values (idempotent, deterministic).
__global__ void wtrans_kernel(const float* __restrict__ w1, const float* __restrict__ b1,
                              const float* __restrict__ w2, const float* __restrict__ b2,
                              const float* __restrict__ w3, const float* __restrict__ b3,
                              unsigned int* __restrict__ ws) {
    const int tid = threadIdx.x;                    // 256 threads
    if (tid < 256) {                                // B1: k = kk*4 + ch
        int kp = tid >> 4, co = tid & 15;
        int k0 = 2 * kp, k1 = k0 + 1;
        float v0 = (k0 < 24) ? w1[co * 24 + (k0 & 3) * 6 + (k0 >> 2)] : 0.f;
        float v1 = (k1 < 24) ? w1[co * 24 + (k1 & 3) * 6 + (k1 >> 2)] : 0.f;
        ws[tid] = pack2bf(v0, v1);
    }
    for (int p = tid; p < 512; p += 256) {          // B2: k = kk*16 + ci
        int kp = p >> 4, co = p & 15;
        int k0 = 2 * kp, ci0 = k0 & 15, kk = k0 >> 4;
        ws[256 + p] = pack2bf(w2[co * 64 + ci0 * 4 + kk],
                              w2[co * 64 + (ci0 + 1) * 4 + kk]);
    }
    for (int p = tid; p < 1792; p += 256) {         // B3: k = kk*16 + ci
        int kp = p >> 4, co = p & 15;
        int k0 = 2 * kp, ci0 = k0 & 15, kk = k0 >> 4;
        float v0 = (kk < 13) ? w3[co * 208 + ci0 * 13 + kk] : 0.f;
        float v1 = (kk < 13) ? w3[co * 208 + (ci0 + 1) * 13 + kk] : 0.f;
        ws[768 + p] = pack2bf(v0, v1);
    }
    float* wf = (float*)ws;
    if (tid < 16) { wf[2560 + tid] = b1[tid]; wf[2576 + tid] = b2[tid]; wf[2592 + tid] = b3[tid]; }
}

__global__ __launch_bounds__(256, 3) void itl_kernel(
    const float* __restrict__ x,
    const unsigned int* __restrict__ wt,
    float* __restrict__ out)
{
    // 4 independent per-wave slices: o1b 160*24 bf16 + o2e 76*24 bf16 each
    __shared__ __align__(16) unsigned short lds[4 * (160 * 24 + 76 * 24)];

    const int tid  = threadIdx.x;
    const int lane = tid & 63;
    const int wv   = tid >> 6;           // wave = independent row
    const int n    = blockIdx.x * 4 + wv;
    const int co   = lane & 15;          // A-row / B-col / D-col index
    const int g    = lane >> 4;          // 0..3
    const int gh   = g >> 1;             // (l>>5)
    const int cib  = 8 * (g & 1);        // ci base of this lane's A elements

    unsigned short* o1b = lds + wv * (160 * 24 + 76 * 24);   // bf16 o1[t][ci]
    unsigned short* o2e = o1b + 160 * 24;                    // bf16 even-o2 [slot][ci]

    const float4* x4 = reinterpret_cast<const float4*>(x) + (size_t)n * 512;
    const float* wf  = (const float*)wt;
    float* outn = out + (size_t)n * 2304;

    // zero the o2e pad rows 72..75 (read under zero-B k-padding in stage 3)
    if (lane < 48) reinterpret_cast<unsigned int*>(o2e)[72 * 12 + lane] = 0u;

    // ---------------- stage 1: 10 tiles, K=24 pad 32 ---------------------------
    {
        FragU b1f;
        #pragma unroll
        for (int p = 0; p < 4; ++p) b1f.u[p] = wt[(4 * g + p) * 16 + co];
        const float bias1 = wf[2560 + co];
        #pragma unroll
        for (int ti = 0; ti < 10; ++ti) {
            const int j0 = 16 * ti;
            FragU a;
            if (g < 3) {
                const int t = j0 + co;               // x window 3t + (2g, 2g+1)
                float4 xa = x4[3 * t + 2 * g];
                float4 xb = x4[3 * t + 2 * g + 1];   // max idx 482 < 512
                a.u[0] = pack2bf(xa.x, xa.y);
                a.u[1] = pack2bf(xa.z, xa.w);
                a.u[2] = pack2bf(xb.x, xb.y);
                a.u[3] = pack2bf(xb.z, xb.w);
            } else {
                a.u[0] = 0u; a.u[1] = 0u; a.u[2] = 0u; a.u[3] = 0u;  // B zero there
            }
            f32x4 acc = {bias1, bias1, bias1, bias1};
            acc = __builtin_amdgcn_mfma_f32_16x16x32_bf16(a.b, b1f.b, acc, 0, 0, 0);
            const int tD = j0 + 4 * g;               // D row = 4*(l>>4)+r
            #pragma unroll
            for (int r = 0; r < 4; ++r) {
                float v = acc[r]; v = fmaxf(v, 0.01f * v);
                o1b[(tD + r) * 24 + co] = f2bf(v);           // rows <= 159 < 160
                if (ti < 3) outn[(tD + r) * 16 + co] = v;    // scale 0, t<48
            }
        }
    }

    // ---------------- stage 2: 9 tiles x 2 k-steps, K=64 -----------------------
    {
        FragU b2f[2];
        #pragma unroll
        for (int kb = 0; kb < 2; ++kb)
            #pragma unroll
            for (int p = 0; p < 4; ++p)
                b2f[kb].u[p] = wt[256 + (16 * kb + 4 * g + p) * 16 + co];
        const float bias2 = wf[2576 + co];
        #pragma unroll
        for (int ti = 0; ti < 9; ++ti) {
            const int j0 = 16 * ti;
            f32x4 acc = {bias2, bias2, bias2, bias2};
            #pragma unroll
            for (int kb = 0; kb < 2; ++kb) {
                const int row = j0 + co + 2 * (2 * kb + gh);    // <= 149
                FragU a; a.u = *(const u32x4*)&o1b[row * 24 + cib];
                acc = __builtin_amdgcn_mfma_f32_16x16x32_bf16(a.b, b2f[kb].b, acc, 0, 0, 0);
            }
            const int jD = j0 + 4 * g;
            #pragma unroll
            for (int r = 0; r < 4; ++r) {
                float v = acc[r]; v = fmaxf(v, 0.01f * v);
                if ((r & 1) == 0) o2e[((jD + r) >> 1) * 24 + co] = f2bf(v);  // even j
                if (ti < 3) outn[768 + (jD + r) * 16 + co] = v;  // scale 1, j<48
            }
        }
    }

    // ---------------- stage 3: 3 tiles x 7 k-steps, K=208 pad 224 --------------
    {
        FragU b3f[7];
        #pragma unroll
        for (int kb = 0; kb < 7; ++kb)
            #pragma unroll
            for (int p = 0; p < 4; ++p)
                b3f[kb].u[p] = wt[768 + (16 * kb + 4 * g + p) * 16 + co];
        const float bias3 = wf[2592 + co];
        #pragma unroll
        for (int ti = 0; ti < 3; ++ti) {
            const int t0 = 16 * ti;
            f32x4 acc = {bias3, bias3, bias3, bias3};
            #pragma unroll
            for (int kb = 0; kb < 7; ++kb) {
                const int row = t0 + co + 2 * (2 * kb + gh);    // <= 73 < 76
                FragU a; a.u = *(const u32x4*)&o2e[row * 24 + cib];
                acc = __builtin_amdgcn_mfma_f32_16x16x32_bf16(a.b, b3f[kb].b, acc, 0, 0, 0);
            }
            const int tD = t0 + 4 * g;
            #pragma unroll
            for (int r = 0; r < 4; ++r) {
                float v = acc[r]; v = fmaxf(v, 0.01f * v);
                outn[1536 + (tD + r) * 16 + co] = v;            // scale 2
            }
        }
    }
}

extern "C" void kernel_launch(void* const* d_in, const int* in_sizes, int n_in,
                              void* d_out, int out_size, void* d_ws, size_t ws_size,
                              hipStream_t stream) {
    const float* x  = (const float*)d_in[0];
    const float* w1 = (const float*)d_in[1];
    const float* b1 = (const float*)d_in[2];
    const float* w2 = (const float*)d_in[3];
    const float* b2 = (const float*)d_in[4];
    const float* w3 = (const float*)d_in[5];
    const float* b3 = (const float*)d_in[6];
    float* out = (float*)d_out;
    unsigned int* ws = (unsigned int*)d_ws;           // 2608 u32 = 10.4 KB

    wtrans_kernel<<<64, 256, 0, stream>>>(w1, b1, w2, b2, w3, b3, ws);
    itl_kernel<<<2048, 256, 0, stream>>>(x, ws, out); // 4 independent waves/WG
}

// Round 15
// 36.795 us; speedup vs baseline: 1.1452x; 1.0292x over previous
//
#include <hip/hip_runtime.h>

// Inception Temporal Layer — 3 causal VALID conv1d + leaky_relu(0.01).
// x[8192][512][4] f32; w1[16][4][6]; w2[16][16][4]; w3[16][16][13]; out[8192][3][48][16].
// Cone: o3[t<48] <- even o2[0..142] <- o1[0..148] <- x[0..449].
//
// Round 15 = round 8 math with MFMA operands SWAPPED: D = W·X (A=weights,
// B=data). D now holds 4 consecutive co per lane (row=4g+r=co, col=l&15=t):
//  - 36 scattered global dword stores -> 9 dwordx4 (4KB contiguous/wave/instr)
//  - 58 ds_write_b16 -> ~15 ds_write_b64
//  - all bf16 packs via v_cvt_pk_bf16_f32 (1 instr vs ~10)
// k-orders, ds_read_b128 patterns, MFMA k-order unchanged -> same accumulation,
// same RNE rounding -> absmax 0.03125 exactly.
// Frag maps (m89-verified): A row = l&15, k = 8*(l>>4)+e; B col = l&15, same k;
// D col = l&15, row = 4*(l>>4)+r.
// K-orders: stage1 k = kk*4+ch (K=24 pad 32, pad zeroed in W-frag); stages 2/3
// k = kk*16+ci (K=64; K=208 pad 224) so B-frag = 8 consecutive ci = ds_read_b128.

typedef __attribute__((ext_vector_type(8))) short bf16x8;
typedef __attribute__((ext_vector_type(4))) float f32x4;
typedef __attribute__((ext_vector_type(4))) unsigned int u32x4;
typedef __attribute__((ext_vector_type(2))) unsigned int u32x2;

union FragU { u32x4 u; bf16x8 b; };

__device__ __forceinline__ unsigned short f2bf(float f) {   // RTN-even (host-side prep)
    unsigned int u = __builtin_bit_cast(unsigned int, f);
    u += 0x7FFFu + ((u >> 16) & 1u);
    return (unsigned short)(u >> 16);
}
__device__ __forceinline__ unsigned int pack2bf(float lo, float hi) {
    return (unsigned int)f2bf(lo) | ((unsigned int)f2bf(hi) << 16);
}
__device__ __forceinline__ unsigned int cvtpk(float lo, float hi) {   // 1 VALU instr, RNE
    unsigned int r;
    asm("v_cvt_pk_bf16_f32 %0, %1, %2" : "=v"(r) : "v"(lo), "v"(hi));
    return r;
}

// d_ws u32 layout (frag-ready W, bf16 pairs; pair kp holds k=2kp lo, 2kp+1 hi):
//   [0..255]     W1[kp*16+co], k = kk*4+ch  (K=24, kp>=12 -> 0)
//   [256..767]   W2[kp*16+co], k = kk*16+ci (K=64)
//   [768..2559]  W3[kp*16+co], k = kk*16+ci (K=208, kk=13 -> 0)
//   f32: [2560..2575] b1, [2576..2591] b2, [2592..2607] b3
// 64 blocks all write identical values (idempotent, deterministic).
__global__ void wtrans_kernel(const float* __restrict__ w1, const float* __restrict__ b1,
                              const float* __restrict__ w2, const float* __restrict__ b2,
                              const float* __restrict__ w3, const float* __restrict__ b3,
                              unsigned int* __restrict__ ws) {
    const int tid = threadIdx.x;                    // 256 threads
    if (tid < 256) {                                // W1: k = kk*4 + ch
        int kp = tid >> 4, co = tid & 15;
        int k0 = 2 * kp, k1 = k0 + 1;
        float v0 = (k0 < 24) ? w1[co * 24 + (k0 & 3) * 6 + (k0 >> 2)] : 0.f;
        float v1 = (k1 < 24) ? w1[co * 24 + (k1 & 3) * 6 + (k1 >> 2)] : 0.f;
        ws[tid] = pack2bf(v0, v1);
    }
    for (int p = tid; p < 512; p += 256) {          // W2: k = kk*16 + ci
        int kp = p >> 4, co = p & 15;
        int k0 = 2 * kp, ci0 = k0 & 15, kk = k0 >> 4;
        ws[256 + p] = pack2bf(w2[co * 64 + ci0 * 4 + kk],
                              w2[co * 64 + (ci0 + 1) * 4 + kk]);
    }
    for (int p = tid; p < 1792; p += 256) {         // W3: k = kk*16 + ci
        int kp = p >> 4, co = p & 15;
        int k0 = 2 * kp, ci0 = k0 & 15, kk = k0 >> 4;
        float v0 = (kk < 13) ? w3[co * 208 + ci0 * 13 + kk] : 0.f;
        float v1 = (kk < 13) ? w3[co * 208 + (ci0 + 1) * 13 + kk] : 0.f;
        ws[768 + p] = pack2bf(v0, v1);
    }
    float* wf = (float*)ws;
    if (tid < 16) { wf[2560 + tid] = b1[tid]; wf[2576 + tid] = b2[tid]; wf[2592 + tid] = b3[tid]; }
}

__global__ __launch_bounds__(64, 4) void itl_kernel(
    const float* __restrict__ x,
    const unsigned int* __restrict__ wt,
    float* __restrict__ out)
{
    __shared__ __align__(16) unsigned short o1b[160 * 24];  // bf16 o1[t][ci], 48B rows
    __shared__ __align__(16) unsigned short o2e[76 * 24];   // bf16 even-o2 [slot][ci]

    const int lane = threadIdx.x;        // 0..63, one wave per row
    const int n    = blockIdx.x;
    const int tc   = lane & 15;          // B col = time-in-tile; A row = weight co-input
    const int g    = lane >> 4;          // 0..3
    const int gh   = g >> 1;             // (l>>5)
    const int cib  = 8 * (g & 1);        // ci base of this lane's B elements
    const int cob  = 4 * g;              // D row base: lane's output co = cob + r

    const float4* x4 = reinterpret_cast<const float4*>(x) + (size_t)n * 512;
    const float* wf  = (const float*)wt;
    float* outn = out + (size_t)n * 2304;

    // zero the o2e pad rows 72..75 (read under zero-W k-padding in stage 3)
    if (lane < 48) reinterpret_cast<unsigned int*>(o2e)[72 * 12 + lane] = 0u;

    // ---------------- stage 1: 10 tiles, K=24 pad 32 ---------------------------
    {
        FragU wA;                                    // A = W1[row=tc][k=8g+e]
        #pragma unroll
        for (int p = 0; p < 4; ++p) wA.u[p] = wt[(4 * g + p) * 16 + tc];
        const float4 bs = *reinterpret_cast<const float4*>(&wf[2560 + cob]);
        #pragma unroll
        for (int ti = 0; ti < 10; ++ti) {
            const int t = 16 * ti + tc;              // this lane's time position
            FragU xB;                                // B = x[k][col=t]
            if (g < 3) {
                float4 xa = x4[3 * t + 2 * g];       // max idx 482 < 512
                float4 xb = x4[3 * t + 2 * g + 1];
                xB.u[0] = cvtpk(xa.x, xa.y);
                xB.u[1] = cvtpk(xa.z, xa.w);
                xB.u[2] = cvtpk(xb.x, xb.y);
                xB.u[3] = cvtpk(xb.z, xb.w);
            } else {
                xB.u[0] = 0u; xB.u[1] = 0u; xB.u[2] = 0u; xB.u[3] = 0u;  // W pad k>=24
            }
            f32x4 acc = {bs.x, bs.y, bs.z, bs.w};    // bias[cob+r]
            acc = __builtin_amdgcn_mfma_f32_16x16x32_bf16(wA.b, xB.b, acc, 0, 0, 0);
            const float v0 = fmaxf(acc[0], 0.01f * acc[0]);
            const float v1 = fmaxf(acc[1], 0.01f * acc[1]);
            const float v2 = fmaxf(acc[2], 0.01f * acc[2]);
            const float v3 = fmaxf(acc[3], 0.01f * acc[3]);
            u32x2 pk = {cvtpk(v0, v1), cvtpk(v2, v3)};
            *reinterpret_cast<u32x2*>(&o1b[t * 24 + cob]) = pk;   // 4 consecutive ci
            if (ti < 3) {                            // scale 0, t<48
                f32x4 o = {v0, v1, v2, v3};
                *reinterpret_cast<f32x4*>(&outn[t * 16 + cob]) = o;
            }
        }
    }

    // ---------------- stage 2: 9 tiles x 2 k-steps, K=64 -----------------------
    {
        FragU w2f[2];                                // A = W2
        #pragma unroll
        for (int kb = 0; kb < 2; ++kb)
            #pragma unroll
            for (int p = 0; p < 4; ++p)
                w2f[kb].u[p] = wt[256 + (16 * kb + 4 * g + p) * 16 + tc];
        const float4 bs = *reinterpret_cast<const float4*>(&wf[2576 + cob]);
        #pragma unroll
        for (int ti = 0; ti < 9; ++ti) {
            const int j = 16 * ti + tc;              // this lane's output position
            f32x4 acc = {bs.x, bs.y, bs.z, bs.w};
            #pragma unroll
            for (int kb = 0; kb < 2; ++kb) {
                const int row = j + 2 * (2 * kb + gh);          // <= 149
                FragU a; a.u = *(const u32x4*)&o1b[row * 24 + cib];
                acc = __builtin_amdgcn_mfma_f32_16x16x32_bf16(w2f[kb].b, a.b, acc, 0, 0, 0);
            }
            const float v0 = fmaxf(acc[0], 0.01f * acc[0]);
            const float v1 = fmaxf(acc[1], 0.01f * acc[1]);
            const float v2 = fmaxf(acc[2], 0.01f * acc[2]);
            const float v3 = fmaxf(acc[3], 0.01f * acc[3]);
            if ((tc & 1) == 0) {                     // even j -> o2e slot j/2
                u32x2 pk = {cvtpk(v0, v1), cvtpk(v2, v3)};
                *reinterpret_cast<u32x2*>(&o2e[(j >> 1) * 24 + cob]) = pk;
            }
            if (ti < 3) {                            // scale 1, j<48
                f32x4 o = {v0, v1, v2, v3};
                *reinterpret_cast<f32x4*>(&outn[768 + j * 16 + cob]) = o;
            }
        }
    }

    // ---------------- stage 3: 3 tiles x 7 k-steps, K=208 pad 224 --------------
    {
        FragU w3f[7];                                // A = W3
        #pragma unroll
        for (int kb = 0; kb < 7; ++kb)
            #pragma unroll
            for (int p = 0; p < 4; ++p)
                w3f[kb].u[p] = wt[768 + (16 * kb + 4 * g + p) * 16 + tc];
        const float4 bs = *reinterpret_cast<const float4*>(&wf[2592 + cob]);
        #pragma unroll
        for (int ti = 0; ti < 3; ++ti) {
            const int t = 16 * ti + tc;
            f32x4 acc = {bs.x, bs.y, bs.z, bs.w};
            #pragma unroll
            for (int kb = 0; kb < 7; ++kb) {
                const int row = t + 2 * (2 * kb + gh);          // <= 73 < 76
                FragU a; a.u = *(const u32x4*)&o2e[row * 24 + cib];
                acc = __builtin_amdgcn_mfma_f32_16x16x32_bf16(w3f[kb].b, a.b, acc, 0, 0, 0);
            }
            const float v0 = fmaxf(acc[0], 0.01f * acc[0]);
            const float v1 = fmaxf(acc[1], 0.01f * acc[1]);
            const float v2 = fmaxf(acc[2], 0.01f * acc[2]);
            const float v3 = fmaxf(acc[3], 0.01f * acc[3]);
            f32x4 o = {v0, v1, v2, v3};
            *reinterpret_cast<f32x4*>(&outn[1536 + t * 16 + cob]) = o;   // scale 2
        }
    }
}

extern "C" void kernel_launch(void* const* d_in, const int* in_sizes, int n_in,
                              void* d_out, int out_size, void* d_ws, size_t ws_size,
                              hipStream_t stream) {
    const float* x  = (const float*)d_in[0];
    const float* w1 = (const float*)d_in[1];
    const float* b1 = (const float*)d_in[2];
    const float* w2 = (const float*)d_in[3];
    const float* b2 = (const float*)d_in[4];
    const float* w3 = (const float*)d_in[5];
    const float* b3 = (const float*)d_in[6];
    float* out = (float*)d_out;
    unsigned int* ws = (unsigned int*)d_ws;           // 2608 u32 = 10.4 KB

    wtrans_kernel<<<64, 256, 0, stream>>>(w1, b1, w2, b2, w3, b3, ws);
    itl_kernel<<<8192, 64, 0, stream>>>(x, ws, out);  // 1 row per wave
}

// Round 16
// 34.242 us; speedup vs baseline: 1.2306x; 1.0745x over previous
//
#include <hip/hip_runtime.h>

// Inception Temporal Layer — 3 causal VALID conv1d + leaky_relu(0.01).
// x[8192][512][4] f32; w1[16][4][6]; w2[16][16][4]; w3[16][16][13]; out[8192][3][48][16].
// Cone: o3[t<48] <- even o2[0..142] <- o1[0..148] <- x[0..449].
//
// Round 16 = round 15 (swapped MFMA D=W·X, contiguous stores, cvt_pk packs)
// with LDS per row HALVED (stride 24 -> 16): 11.3KB -> 7.6KB/row.
// Theory: wall = (32 rows/CU / resident rows) x 12.5us per-row latency;
// resident rows was LDS-capped at 13 in ALL null experiments (r10-r15).
// 7.6KB -> 21 rows resident -> predicted 22-26us. Math byte-identical to r15
// (same k-orders, accumulation, RNE rounding) -> absmax 0.03125 exactly.
//
// Frag maps (m89-verified): A row = l&15, k = 8*(l>>4)+e; B col = l&15, same k;
// D col = l&15, row = 4*(l>>4)+r.
// K-orders: stage1 k = kk*4+ch (K=24 pad 32, pad zeroed in W-frag); stages 2/3
// k = kk*16+ci (K=64; K=208 pad 224) so B-frag = 8 consecutive ci = ds_read_b128.

typedef __attribute__((ext_vector_type(8))) short bf16x8;
typedef __attribute__((ext_vector_type(4))) float f32x4;
typedef __attribute__((ext_vector_type(4))) unsigned int u32x4;
typedef __attribute__((ext_vector_type(2))) unsigned int u32x2;

union FragU { u32x4 u; bf16x8 b; };

__device__ __forceinline__ unsigned short f2bf(float f) {   // RTN-even (prep kernel)
    unsigned int u = __builtin_bit_cast(unsigned int, f);
    u += 0x7FFFu + ((u >> 16) & 1u);
    return (unsigned short)(u >> 16);
}
__device__ __forceinline__ unsigned int pack2bf(float lo, float hi) {
    return (unsigned int)f2bf(lo) | ((unsigned int)f2bf(hi) << 16);
}
__device__ __forceinline__ unsigned int cvtpk(float lo, float hi) {   // 1 VALU instr, RNE
    unsigned int r;
    asm("v_cvt_pk_bf16_f32 %0, %1, %2" : "=v"(r) : "v"(lo), "v"(hi));
    return r;
}

// d_ws u32 layout (frag-ready W, bf16 pairs; pair kp holds k=2kp lo, 2kp+1 hi):
//   [0..255]     W1[kp*16+co], k = kk*4+ch  (K=24, kp>=12 -> 0)
//   [256..767]   W2[kp*16+co], k = kk*16+ci (K=64)
//   [768..2559]  W3[kp*16+co], k = kk*16+ci (K=208, kk=13 -> 0)
//   f32: [2560..2575] b1, [2576..2591] b2, [2592..2607] b3
// 64 blocks all write identical values (idempotent, deterministic).
__global__ void wtrans_kernel(const float* __restrict__ w1, const float* __restrict__ b1,
                              const float* __restrict__ w2, const float* __restrict__ b2,
                              const float* __restrict__ w3, const float* __restrict__ b3,
                              unsigned int* __restrict__ ws) {
    const int tid = threadIdx.x;                    // 256 threads
    if (tid < 256) {                                // W1: k = kk*4 + ch
        int kp = tid >> 4, co = tid & 15;
        int k0 = 2 * kp, k1 = k0 + 1;
        float v0 = (k0 < 24) ? w1[co * 24 + (k0 & 3) * 6 + (k0 >> 2)] : 0.f;
        float v1 = (k1 < 24) ? w1[co * 24 + (k1 & 3) * 6 + (k1 >> 2)] : 0.f;
        ws[tid] = pack2bf(v0, v1);
    }
    for (int p = tid; p < 512; p += 256) {          // W2: k = kk*16 + ci
        int kp = p >> 4, co = p & 15;
        int k0 = 2 * kp, ci0 = k0 & 15, kk = k0 >> 4;
        ws[256 + p] = pack2bf(w2[co * 64 + ci0 * 4 + kk],
                              w2[co * 64 + (ci0 + 1) * 4 + kk]);
    }
    for (int p = tid; p < 1792; p += 256) {         // W3: k = kk*16 + ci
        int kp = p >> 4, co = p & 15;
        int k0 = 2 * kp, ci0 = k0 & 15, kk = k0 >> 4;
        float v0 = (kk < 13) ? w3[co * 208 + ci0 * 13 + kk] : 0.f;
        float v1 = (kk < 13) ? w3[co * 208 + (ci0 + 1) * 13 + kk] : 0.f;
        ws[768 + p] = pack2bf(v0, v1);
    }
    float* wf = (float*)ws;
    if (tid < 16) { wf[2560 + tid] = b1[tid]; wf[2576 + tid] = b2[tid]; wf[2592 + tid] = b3[tid]; }
}

__global__ __launch_bounds__(64, 4) void itl_kernel(
    const float* __restrict__ x,
    const unsigned int* __restrict__ wt,
    float* __restrict__ out)
{
    __shared__ __align__(16) unsigned short o1b[160 * 16];  // bf16 o1[t][ci], 32B rows
    __shared__ __align__(16) unsigned short o2e[76 * 16];   // bf16 even-o2 [slot][ci]

    const int lane = threadIdx.x;        // 0..63, one wave per row
    const int n    = blockIdx.x;
    const int tc   = lane & 15;          // B col = time-in-tile; A row = weight row
    const int g    = lane >> 4;          // 0..3
    const int gh   = g >> 1;             // (l>>5)
    const int cib  = 8 * (g & 1);        // ci base of this lane's B elements
    const int cob  = 4 * g;              // D row base: lane's output co = cob + r

    const float4* x4 = reinterpret_cast<const float4*>(x) + (size_t)n * 512;
    const float* wf  = (const float*)wt;
    float* outn = out + (size_t)n * 2304;

    // zero the o2e pad rows 72..75 (64 shorts = 32 dwords)
    if (lane < 32) reinterpret_cast<unsigned int*>(o2e)[72 * 8 + lane] = 0u;

    // ---------------- stage 1: 10 tiles, K=24 pad 32 ---------------------------
    {
        FragU wA;                                    // A = W1[row=tc][k=8g+e]
        #pragma unroll
        for (int p = 0; p < 4; ++p) wA.u[p] = wt[(4 * g + p) * 16 + tc];
        const float4 bs = *reinterpret_cast<const float4*>(&wf[2560 + cob]);
        #pragma unroll
        for (int ti = 0; ti < 10; ++ti) {
            const int t = 16 * ti + tc;              // this lane's time position
            FragU xB;                                // B = x[k][col=t]
            if (g < 3) {
                float4 xa = x4[3 * t + 2 * g];       // max idx 482 < 512
                float4 xb = x4[3 * t + 2 * g + 1];
                xB.u[0] = cvtpk(xa.x, xa.y);
                xB.u[1] = cvtpk(xa.z, xa.w);
                xB.u[2] = cvtpk(xb.x, xb.y);
                xB.u[3] = cvtpk(xb.z, xb.w);
            } else {
                xB.u[0] = 0u; xB.u[1] = 0u; xB.u[2] = 0u; xB.u[3] = 0u;  // W pad k>=24
            }
            f32x4 acc = {bs.x, bs.y, bs.z, bs.w};    // bias[cob+r]
            acc = __builtin_amdgcn_mfma_f32_16x16x32_bf16(wA.b, xB.b, acc, 0, 0, 0);
            const float v0 = fmaxf(acc[0], 0.01f * acc[0]);
            const float v1 = fmaxf(acc[1], 0.01f * acc[1]);
            const float v2 = fmaxf(acc[2], 0.01f * acc[2]);
            const float v3 = fmaxf(acc[3], 0.01f * acc[3]);
            u32x2 pk = {cvtpk(v0, v1), cvtpk(v2, v3)};
            *reinterpret_cast<u32x2*>(&o1b[t * 16 + cob]) = pk;   // 4 consecutive ci
            if (ti < 3) {                            // scale 0, t<48
                f32x4 o = {v0, v1, v2, v3};
                *reinterpret_cast<f32x4*>(&outn[t * 16 + cob]) = o;
            }
        }
    }

    // ---------------- stage 2: 9 tiles x 2 k-steps, K=64 -----------------------
    {
        FragU w2f[2];                                // A = W2
        #pragma unroll
        for (int kb = 0; kb < 2; ++kb)
            #pragma unroll
            for (int p = 0; p < 4; ++p)
                w2f[kb].u[p] = wt[256 + (16 * kb + 4 * g + p) * 16 + tc];
        const float4 bs = *reinterpret_cast<const float4*>(&wf[2576 + cob]);
        #pragma unroll
        for (int ti = 0; ti < 9; ++ti) {
            const int j = 16 * ti + tc;              // this lane's output position
            f32x4 acc = {bs.x, bs.y, bs.z, bs.w};
            #pragma unroll
            for (int kb = 0; kb < 2; ++kb) {
                const int row = j + 2 * (2 * kb + gh);          // <= 149 < 160
                FragU a; a.u = *(const u32x4*)&o1b[row * 16 + cib];
                acc = __builtin_amdgcn_mfma_f32_16x16x32_bf16(w2f[kb].b, a.b, acc, 0, 0, 0);
            }
            const float v0 = fmaxf(acc[0], 0.01f * acc[0]);
            const float v1 = fmaxf(acc[1], 0.01f * acc[1]);
            const float v2 = fmaxf(acc[2], 0.01f * acc[2]);
            const float v3 = fmaxf(acc[3], 0.01f * acc[3]);
            if ((tc & 1) == 0) {                     // even j -> o2e slot j/2
                u32x2 pk = {cvtpk(v0, v1), cvtpk(v2, v3)};
                *reinterpret_cast<u32x2*>(&o2e[(j >> 1) * 16 + cob]) = pk;
            }
            if (ti < 3) {                            // scale 1, j<48
                f32x4 o = {v0, v1, v2, v3};
                *reinterpret_cast<f32x4*>(&outn[768 + j * 16 + cob]) = o;
            }
        }
    }

    // ---------------- stage 3: 3 tiles x 7 k-steps, K=208 pad 224 --------------
    {
        FragU w3f[7];                                // A = W3
        #pragma unroll
        for (int kb = 0; kb < 7; ++kb)
            #pragma unroll
            for (int p = 0; p < 4; ++p)
                w3f[kb].u[p] = wt[768 + (16 * kb + 4 * g + p) * 16 + tc];
        const float4 bs = *reinterpret_cast<const float4*>(&wf[2592 + cob]);
        #pragma unroll
        for (int ti = 0; ti < 3; ++ti) {
            const int t = 16 * ti + tc;
            f32x4 acc = {bs.x, bs.y, bs.z, bs.w};
            #pragma unroll
            for (int kb = 0; kb < 7; ++kb) {
                const int row = t + 2 * (2 * kb + gh);          // <= 73 < 76
                FragU a; a.u = *(const u32x4*)&o2e[row * 16 + cib];
                acc = __builtin_amdgcn_mfma_f32_16x16x32_bf16(w3f[kb].b, a.b, acc, 0, 0, 0);
            }
            const float v0 = fmaxf(acc[0], 0.01f * acc[0]);
            const float v1 = fmaxf(acc[1], 0.01f * acc[1]);
            const float v2 = fmaxf(acc[2], 0.01f * acc[2]);
            const float v3 = fmaxf(acc[3], 0.01f * acc[3]);
            f32x4 o = {v0, v1, v2, v3};
            *reinterpret_cast<f32x4*>(&outn[1536 + t * 16 + cob]) = o;   // scale 2
        }
    }
}

extern "C" void kernel_launch(void* const* d_in, const int* in_sizes, int n_in,
                              void* d_out, int out_size, void* d_ws, size_t ws_size,
                              hipStream_t stream) {
    const float* x  = (const float*)d_in[0];
    const float* w1 = (const float*)d_in[1];
    const float* b1 = (const float*)d_in[2];
    const float* w2 = (const float*)d_in[3];
    const float* b2 = (const float*)d_in[4];
    const float* w3 = (const float*)d_in[5];
    const float* b3 = (const float*)d_in[6];
    float* out = (float*)d_out;
    unsigned int* ws = (unsigned int*)d_ws;           // 2608 u32 = 10.4 KB

    wtrans_kernel<<<64, 256, 0, stream>>>(w1, b1, w2, b2, w3, b3, ws);
    itl_kernel<<<8192, 64, 0, stream>>>(x, ws, out);  // 1 row per wave, 7.6KB LDS
}